// Round 6
// baseline (200.553 us; speedup 1.0000x reference)
//
#include <hip/hip_runtime.h>
#include <math.h>

#define BB 32
#define NN 1024
#define DD 128

typedef __bf16 bf16;
typedef bf16 bf16x4 __attribute__((ext_vector_type(4)));
typedef bf16 bf16x8 __attribute__((ext_vector_type(8)));
typedef float f32x4 __attribute__((ext_vector_type(4)));
typedef float f32x16 __attribute__((ext_vector_type(16)));

#define MFMA16(a, b, c) __builtin_amdgcn_mfma_f32_16x16x32_bf16(a, b, c, 0, 0, 0)
#define MFMA32(a, b, c) __builtin_amdgcn_mfma_f32_32x32x16_bf16(a, b, c, 0, 0, 0)

__device__ inline bf16x4 swap32(bf16x4 v) {
    union { bf16x4 h; int i[2]; } u, r;
    u.h = v;
    r.i[0] = __shfl_xor(u.i[0], 32, 64);
    r.i[1] = __shfl_xor(u.i[1], 32, 64);
    return r.h;
}

// ---------------- K0: prep (all global accesses coalesced via LDS tile) ----------
// Xbf[b*N+n][0:128]=bf16(P); Pq=bf16(P*wc); Ptp[b][d][n]=bf16(P[b][n][d]);
// t[b][n]=P_n.wa  (wb is dead: constant over softmax axis)
#define LTS 133
__global__ __launch_bounds__(256) void k_prep(const float* __restrict__ P,
                                              const float* __restrict__ w_itr,
                                              bf16* __restrict__ Xbf,
                                              bf16* __restrict__ Pq,
                                              bf16* __restrict__ Ptp,
                                              float* __restrict__ t) {
    __shared__ float Lt[64 * LTS];
    int tid = threadIdx.x;
    int b = blockIdx.x >> 4, g = blockIdx.x & 15;
    int n0 = g * 64;
    long base = ((long)b * NN + n0) * DD;
#pragma unroll
    for (int i = 0; i < 8; ++i) {
        int idx = tid + i * 256;           // 0..2047 f4-chunks
        int row = idx >> 5, c4 = idx & 31;
        *(float4*)&Lt[row * LTS + c4 * 4] = *(const float4*)&P[base + row * 128 + c4 * 4];
    }
    __syncthreads();
    {   // t = P . wa, k interleaved to avoid bank conflicts
        int row = tid >> 2, q = tid & 3;
        float s = 0.f;
#pragma unroll
        for (int kk = 0; kk < 32; ++kk) {
            int k = 4 * kk + q;
            s += Lt[row * LTS + k] * w_itr[k];
        }
        s += __shfl_xor(s, 1);
        s += __shfl_xor(s, 2);
        if (q == 0) t[(long)b * NN + n0 + row] = s;
    }
    const float* wc = w_itr + 2 * DD;
#pragma unroll
    for (int i = 0; i < 4; ++i) {
        int idx = tid + i * 256;           // 0..1023 8-elem chunks
        int row = idx >> 4, seg = idx & 15;
        float4 va = *(const float4*)&Lt[row * LTS + seg * 8];
        float4 vb = *(const float4*)&Lt[row * LTS + seg * 8 + 4];
        float4 wa4 = *(const float4*)&wc[seg * 8];
        float4 wb4 = *(const float4*)&wc[seg * 8 + 4];
        float fv[8] = {va.x, va.y, va.z, va.w, vb.x, vb.y, vb.z, vb.w};
        float wv[8] = {wa4.x, wa4.y, wa4.z, wa4.w, wb4.x, wb4.y, wb4.z, wb4.w};
        bf16x8 xv, qv;
#pragma unroll
        for (int e = 0; e < 8; ++e) {
            xv[e] = (bf16)fv[e];
            qv[e] = (bf16)(fv[e] * wv[e]);
        }
        long rowg = (long)b * NN + n0 + row;
        *(bf16x8*)&Xbf[rowg * 128 + seg * 8] = xv;
        *(bf16x8*)&Pq[rowg * 128 + seg * 8] = qv;
    }
#pragma unroll
    for (int i = 0; i < 4; ++i) {
        int idx = tid + i * 256;           // d-major chunks
        int d = idx >> 3, c = idx & 7;
        bf16x8 v;
#pragma unroll
        for (int e = 0; e < 8; ++e) v[e] = (bf16)Lt[(c * 8 + e) * LTS + d];
        *(bf16x8*)&Ptp[((long)b * DD + d) * NN + n0 + c * 8] = v;
    }
}

// ---------------- K0b: weight transpose (LDS-tiled) ----------------
// WtG[mat*128 + col][k] = bf16(w_mat[k][col])
__global__ __launch_bounds__(256) void k_prepw(const float* __restrict__ w1,
                                               const float* __restrict__ w2,
                                               const float* __restrict__ w3,
                                               bf16* __restrict__ WtG) {
    __shared__ float Lw[32][33];
    int bi = blockIdx.x;                 // 96 = 3 mats * 8 kt * 4 ct
    int mat = bi >> 5, rem = bi & 31;
    int kt = rem >> 2, ct = rem & 3;
    const float* wsrc = (mat == 0) ? w1 : ((mat == 1) ? w2 : w3);
    int tid = threadIdx.x;
#pragma unroll
    for (int p = 0; p < 4; ++p) {
        int idx = tid + p * 256;
        int kr = idx >> 5, c = idx & 31;
        Lw[kr][c] = wsrc[(kt * 32 + kr) * DD + ct * 32 + c];
    }
    __syncthreads();
    int colg = tid >> 3, kq = tid & 7;
    bf16x4 v;
#pragma unroll
    for (int e = 0; e < 4; ++e) v[e] = (bf16)Lw[kq * 4 + e][colg];
    *(bf16x4*)&WtG[(mat * 128 + ct * 32 + colg) * 256 + kt * 32 + kq * 4] = v;
}

// ---------------- K1: fused attention + gated MLP ----------------
// 4 waves = 2 row-groups (rg: 32 q-rows) x 2 key-halves (kh: 32 keys of each
// 64-key iter tile). S^T = K*Q^T; P=exp(S+t); O^T = V^T*P (no-max streaming
// softmax: logits provably tiny, clamp 80). Tail: X=[P|attn] in LDS, W staged
// per (mat, 64-k phase) in LDS — 4 phases cover k=0..255 — 3 fused GEMMs,
// out written 64B-chunk coalesced.
__global__ __launch_bounds__(256, 3) void k_attn(const bf16* __restrict__ Xbf,
                                                 const bf16* __restrict__ Pq,
                                                 const bf16* __restrict__ Ptp,
                                                 const float* __restrict__ t,
                                                 const bf16* __restrict__ WtG,
                                                 const float* __restrict__ b1,
                                                 const float* __restrict__ b2,
                                                 const float* __restrict__ b3,
                                                 float* __restrict__ out) {
    __shared__ __align__(16) char smem[52736];
    bf16* Kt = (bf16*)smem;                  // [64][136]   0..17408
    bf16* Vt = (bf16*)(smem + 17408);        // [128][72]   17408..35840
    float* tsh = (float*)(smem + 35840);     // [64]        35840..36096
    float* lbuf = (float*)(smem + 52224);    // [4][32]     52224..52736
    bf16* Xsh = (bf16*)smem;                 // alias [64][264]  0..33792
    bf16* Obf = (bf16*)(smem + 33792);       // alias [256][36]  33792..52224
    bf16* Wst = (bf16*)(smem + 33792);       // alias [128][72]  (after Obf dead)

    const int tid = threadIdx.x;
    const int w = tid >> 6, lane = tid & 63;
    const int col = lane & 31, q = lane >> 5;
    const int kh = w >> 1, rg = w & 1;
    const int b = blockIdx.x & 31, qt = blockIdx.x >> 5;
    const long qrow0 = (long)b * NN + qt * 64;
    const long qbase = qrow0 + rg * 32;

    bf16x8 Qb[8];
#pragma unroll
    for (int c = 0; c < 8; ++c)
        Qb[c] = *(const bf16x8*)&Pq[(qbase + col) * 128 + c * 16 + q * 8];

    f32x16 O[4];
#pragma unroll
    for (int mt = 0; mt < 4; ++mt)
#pragma unroll
        for (int r = 0; r < 16; ++r) O[mt][r] = 0.f;
    float lsum = 0.f;

    float4 kr[4], vr[4];
    float tr = 0.f;
    auto loadKV = [&](int jt) {
        int j0 = jt * 64;
#pragma unroll
        for (int i = 0; i < 4; ++i) {
            int idx = tid + i * 256;        // K: key=idx>>4, c16=idx&15
            kr[i] = *(const float4*)&Xbf[((long)b * NN + j0 + (idx >> 4)) * 128 +
                                         (idx & 15) * 8];
            vr[i] = *(const float4*)&Ptp[((long)b * DD + (idx >> 3)) * NN + j0 +
                                         (idx & 7) * 8];
        }
        tr = (tid < 64) ? t[(long)b * NN + j0 + tid] : 0.f;
    };

    loadKV(0);
    for (int jt = 0; jt < 16; ++jt) {
        __syncthreads();
#pragma unroll
        for (int i = 0; i < 4; ++i) {
            int idx = tid + i * 256;
            *(float4*)&Kt[(idx >> 4) * 136 + (idx & 15) * 8] = kr[i];
            *(float4*)&Vt[(idx >> 3) * 72 + (idx & 7) * 8] = vr[i];
        }
        if (tid < 64) tsh[tid] = tr;
        __syncthreads();
        if (jt < 15) loadKV(jt + 1);

        const bf16* KtH = Kt + kh * 32 * 136;
        const float* tH = tsh + kh * 32;

        f32x16 S;
#pragma unroll
        for (int r = 0; r < 16; ++r) S[r] = 0.f;
#pragma unroll
        for (int c = 0; c < 8; ++c)
            S = MFMA32(*(const bf16x8*)&KtH[col * 136 + c * 16 + q * 8], Qb[c], S);
        float tqs[16];
#pragma unroll
        for (int i = 0; i < 4; ++i) {
            float4 tv = *(const float4*)&tH[8 * i + 4 * q];
            tqs[4 * i + 0] = tv.x; tqs[4 * i + 1] = tv.y;
            tqs[4 * i + 2] = tv.z; tqs[4 * i + 3] = tv.w;
        }
        float pv[16];
#pragma unroll
        for (int r = 0; r < 16; ++r) {
            float e = __expf(fminf(S[r] + tqs[r], 80.f));
            pv[r] = e;
            lsum += e;
        }
        bf16x4 Qd[4];
#pragma unroll
        for (int i = 0; i < 4; ++i)
#pragma unroll
            for (int e = 0; e < 4; ++e) Qd[i][e] = (bf16)pv[4 * i + e];
        bf16x4 sA = q ? Qd[0] : Qd[1];
        bf16x4 rA = swap32(sA);
        bf16x4 sB = q ? Qd[2] : Qd[3];
        bf16x4 rB = swap32(sB);
        bf16x4 lo0 = q ? rA : Qd[0], hi0 = q ? Qd[1] : rA;
        bf16x4 lo1 = q ? rB : Qd[2], hi1 = q ? Qd[3] : rB;
        bf16x8 f0, f1;
#pragma unroll
        for (int e = 0; e < 4; ++e) {
            f0[e] = lo0[e]; f0[4 + e] = hi0[e];
            f1[e] = lo1[e]; f1[4 + e] = hi1[e];
        }
#pragma unroll
        for (int mt = 0; mt < 4; ++mt) {
            O[mt] = MFMA32(*(const bf16x8*)&Vt[(mt * 32 + col) * 72 + kh * 32 + q * 8],
                           f0, O[mt]);
            O[mt] = MFMA32(*(const bf16x8*)&Vt[(mt * 32 + col) * 72 + kh * 32 + 16 + q * 8],
                           f1, O[mt]);
        }
    }

    // ---- merge kh halves into Xsh = [P | attn] (bf16) ----
    float l2 = lsum + __shfl_xor(lsum, 32, 64);
    if (q == 0) lbuf[(kh * 2 + rg) * 32 + col] = l2;
    __syncthreads();                    // Kt/Vt dead past here
    if (kh == 1) {
#pragma unroll
        for (int mt = 0; mt < 4; ++mt)
#pragma unroll
            for (int r = 0; r < 16; ++r) {
                int d = mt * 32 + (r & 3) + 8 * (r >> 2) + 4 * q;
                Obf[(rg * 128 + d) * 36 + col] = (bf16)O[mt][r];
            }
    } else {
        // kh0 waves (tid<128): stage P-half of X coalesced from global
#pragma unroll
        for (int i = 0; i < 8; ++i) {
            int idx = tid + i * 128;     // 0..1023
            int row = idx >> 4, seg = idx & 15;
            *(bf16x8*)&Xsh[row * 264 + seg * 8] =
                *(const bf16x8*)&Xbf[(qrow0 + row) * 128 + seg * 8];
        }
    }
    __syncthreads();
    if (kh == 0) {
        float linv = 1.f / (lbuf[rg * 32 + col] + lbuf[(2 + rg) * 32 + col]);
#pragma unroll
        for (int mt = 0; mt < 4; ++mt)
#pragma unroll
            for (int r = 0; r < 16; ++r) {
                int d = mt * 32 + (r & 3) + 8 * (r >> 2) + 4 * q;
                float v = (O[mt][r] + (float)Obf[(rg * 128 + d) * 36 + col]) * linv;
                Xsh[(rg * 32 + col) * 264 + 128 + d] = (bf16)v;
            }
    }

    // ---- fused gated MLP: Y_m = X @ W_m, W staged in LDS per (mat, 64-k phase) ----
    const int ln = lane & 15, q3 = lane >> 4;
    f32x4 gz[8], gr[8];
#pragma unroll
    for (int mat = 0; mat < 3; ++mat) {
        f32x4 acc[8];
#pragma unroll
        for (int nt = 0; nt < 8; ++nt) acc[nt] = (f32x4){0.f, 0.f, 0.f, 0.f};
#pragma unroll
        for (int k2 = 0; k2 < 4; ++k2) {   // FOUR 64-k phases: k = 0..255
            __syncthreads();             // also protects Xsh build (first iter) / Obf death
#pragma unroll
            for (int i = 0; i < 4; ++i) {
                int idx = tid + i * 256; // 0..1023: colw=idx>>3, kc8=idx&7
                *(float4*)&Wst[(idx >> 3) * 72 + (idx & 7) * 8] =
                    *(const float4*)&WtG[(mat * 128 + (idx >> 3)) * 256 + k2 * 64 +
                                         (idx & 7) * 8];
            }
            __syncthreads();
#pragma unroll
            for (int kc2 = 0; kc2 < 2; ++kc2) {
                bf16x8 Af = *(const bf16x8*)&Xsh[(w * 16 + ln) * 264 + k2 * 64 +
                                                 kc2 * 32 + q3 * 8];
#pragma unroll
                for (int nt = 0; nt < 8; ++nt) {
                    bf16x8 Bf = *(const bf16x8*)&Wst[(nt * 16 + ln) * 72 + kc2 * 32 + q3 * 8];
                    acc[nt] = MFMA16(Af, Bf, acc[nt]);
                }
            }
        }
        const float* bp = (mat == 0) ? b1 : ((mat == 1) ? b2 : b3);
#pragma unroll
        for (int nt = 0; nt < 8; ++nt) {
            int colc = nt * 16 + ln;
            float bb = bp[colc];
#pragma unroll
            for (int r = 0; r < 4; ++r) {
                float y = acc[nt][r] + bb;
                if (mat == 0) gz[nt][r] = tanhf(y);
                else if (mat == 1) gr[nt][r] = 1.f / (1.f + __expf(-y));
                else {
                    float fg = 1.f / (1.f + __expf(-y));
                    int lrow = w * 16 + q3 * 4 + r;
                    float p = (float)Xsh[lrow * 264 + colc];
                    out[(qrow0 + lrow) * 128 + colc] = gr[nt][r] * p + fg * gz[nt][r];
                }
            }
        }
    }
}

extern "C" void kernel_launch(void* const* d_in, const int* in_sizes, int n_in,
                              void* d_out, int out_size, void* d_ws, size_t ws_size,
                              hipStream_t stream) {
    const float* P     = (const float*)d_in[0];
    const float* w_itr = (const float*)d_in[1];
    const float* w1    = (const float*)d_in[2];
    const float* w2    = (const float*)d_in[3];
    const float* w3    = (const float*)d_in[4];
    const float* b1    = (const float*)d_in[5];
    const float* b2    = (const float*)d_in[6];
    const float* b3    = (const float*)d_in[7];
    float* out = (float*)d_out;

    char* wsb = (char*)d_ws;
    bf16* Xbf  = (bf16*)(wsb);                    //  8,388,608 B
    bf16* Pq   = (bf16*)(wsb + 8388608);          //  8,388,608 B
    bf16* Ptp  = (bf16*)(wsb + 16777216);         //  8,388,608 B
    float* tws = (float*)(wsb + 25165824);        //    131,072 B
    bf16* WtG  = (bf16*)(wsb + 25296896);         //    196,608 B

    k_prep<<<dim3(BB * 16), dim3(256), 0, stream>>>(P, w_itr, Xbf, Pq, Ptp, tws);
    k_prepw<<<dim3(96), dim3(256), 0, stream>>>(w1, w2, w3, WtG);
    k_attn<<<dim3(512), dim3(256), 0, stream>>>(Xbf, Pq, Ptp, tws, WtG, b1, b2, b3, out);
}

// Round 7
// 176.569 us; speedup vs baseline: 1.1358x; 1.1358x over previous
//
#include <hip/hip_runtime.h>
#include <math.h>

#define BB 32
#define NN 1024
#define DD 128

typedef __bf16 bf16;
typedef bf16 bf16x4 __attribute__((ext_vector_type(4)));
typedef bf16 bf16x8 __attribute__((ext_vector_type(8)));
typedef float f32x4 __attribute__((ext_vector_type(4)));
typedef float f32x16 __attribute__((ext_vector_type(16)));

#define MFMA16(a, b, c) __builtin_amdgcn_mfma_f32_16x16x32_bf16(a, b, c, 0, 0, 0)
#define MFMA32(a, b, c) __builtin_amdgcn_mfma_f32_32x32x16_bf16(a, b, c, 0, 0, 0)

__device__ inline bf16x4 swap32(bf16x4 v) {
    union { bf16x4 h; int i[2]; } u, r;
    u.h = v;
    r.i[0] = __shfl_xor(u.i[0], 32, 64);
    r.i[1] = __shfl_xor(u.i[1], 32, 64);
    return r.h;
}

// ---------------- K0: prep (all global accesses coalesced via LDS tile) ----------
// Xbf[b*N+n][0:128]=bf16(P); Pq=bf16(P*wc); Ptp[b][d][n]=bf16(P[b][n][d]);
// t[b][n]=P_n.wa  (wb is dead: constant over softmax axis)
#define LTS 133
__global__ __launch_bounds__(256) void k_prep(const float* __restrict__ P,
                                              const float* __restrict__ w_itr,
                                              bf16* __restrict__ Xbf,
                                              bf16* __restrict__ Pq,
                                              bf16* __restrict__ Ptp,
                                              float* __restrict__ t) {
    __shared__ float Lt[64 * LTS];
    int tid = threadIdx.x;
    int b = blockIdx.x >> 4, g = blockIdx.x & 15;
    int n0 = g * 64;
    long base = ((long)b * NN + n0) * DD;
#pragma unroll
    for (int i = 0; i < 8; ++i) {
        int idx = tid + i * 256;           // 0..2047 f4-chunks
        int row = idx >> 5, c4 = idx & 31;
        *(float4*)&Lt[row * LTS + c4 * 4] = *(const float4*)&P[base + row * 128 + c4 * 4];
    }
    __syncthreads();
    {   // t = P . wa, k interleaved to avoid bank conflicts
        int row = tid >> 2, q = tid & 3;
        float s = 0.f;
#pragma unroll
        for (int kk = 0; kk < 32; ++kk) {
            int k = 4 * kk + q;
            s += Lt[row * LTS + k] * w_itr[k];
        }
        s += __shfl_xor(s, 1);
        s += __shfl_xor(s, 2);
        if (q == 0) t[(long)b * NN + n0 + row] = s;
    }
    const float* wc = w_itr + 2 * DD;
#pragma unroll
    for (int i = 0; i < 4; ++i) {
        int idx = tid + i * 256;           // 0..1023 8-elem chunks
        int row = idx >> 4, seg = idx & 15;
        float4 va = *(const float4*)&Lt[row * LTS + seg * 8];
        float4 vb = *(const float4*)&Lt[row * LTS + seg * 8 + 4];
        float4 wa4 = *(const float4*)&wc[seg * 8];
        float4 wb4 = *(const float4*)&wc[seg * 8 + 4];
        float fv[8] = {va.x, va.y, va.z, va.w, vb.x, vb.y, vb.z, vb.w};
        float wv[8] = {wa4.x, wa4.y, wa4.z, wa4.w, wb4.x, wb4.y, wb4.z, wb4.w};
        bf16x8 xv, qv;
#pragma unroll
        for (int e = 0; e < 8; ++e) {
            xv[e] = (bf16)fv[e];
            qv[e] = (bf16)(fv[e] * wv[e]);
        }
        long rowg = (long)b * NN + n0 + row;
        *(bf16x8*)&Xbf[rowg * 128 + seg * 8] = xv;
        *(bf16x8*)&Pq[rowg * 128 + seg * 8] = qv;
    }
#pragma unroll
    for (int i = 0; i < 4; ++i) {
        int idx = tid + i * 256;           // d-major chunks
        int d = idx >> 3, c = idx & 7;
        bf16x8 v;
#pragma unroll
        for (int e = 0; e < 8; ++e) v[e] = (bf16)Lt[(c * 8 + e) * LTS + d];
        *(bf16x8*)&Ptp[((long)b * DD + d) * NN + n0 + c * 8] = v;
    }
}

// ---------------- K0b: weight transpose (LDS-tiled) ----------------
// WtG[mat*128 + col][k] = bf16(w_mat[k][col])
__global__ __launch_bounds__(256) void k_prepw(const float* __restrict__ w1,
                                               const float* __restrict__ w2,
                                               const float* __restrict__ w3,
                                               bf16* __restrict__ WtG) {
    __shared__ float Lw[32][33];
    int bi = blockIdx.x;                 // 96 = 3 mats * 8 kt * 4 ct
    int mat = bi >> 5, rem = bi & 31;
    int kt = rem >> 2, ct = rem & 3;
    const float* wsrc = (mat == 0) ? w1 : ((mat == 1) ? w2 : w3);
    int tid = threadIdx.x;
#pragma unroll
    for (int p = 0; p < 4; ++p) {
        int idx = tid + p * 256;
        int kr = idx >> 5, c = idx & 31;
        Lw[kr][c] = wsrc[(kt * 32 + kr) * DD + ct * 32 + c];
    }
    __syncthreads();
    int colg = tid >> 3, kq = tid & 7;
    bf16x4 v;
#pragma unroll
    for (int e = 0; e < 4; ++e) v[e] = (bf16)Lw[kq * 4 + e][colg];
    *(bf16x4*)&WtG[(mat * 128 + ct * 32 + colg) * 256 + kt * 32 + kq * 4] = v;
}

// ---------------- K1: fused attention + gated MLP, barrier-free main loop ----
// Block = 4 waves; wave kh owns ALL 32 q-rows x keys [kh*256, kh*256+256).
// All MFMA operands are direct 16B global loads (L2-resident, XCD-affine b).
// S^T = K*Q^T; P=exp(S+t); O^T = V^T*P (no-max streaming softmax; logits tiny).
// Merge: two-stage fp32 LDS reduction. Tail: fused gated MLP on X=[P|attn],
// out staged via LDS -> fully-coalesced float4 row stores.
__global__ __launch_bounds__(256, 3) void k_attn(const bf16* __restrict__ Xbf,
                                                 const bf16* __restrict__ Pq,
                                                 const bf16* __restrict__ Ptp,
                                                 const float* __restrict__ t,
                                                 const bf16* __restrict__ WtG,
                                                 const float* __restrict__ b1,
                                                 const float* __restrict__ b2,
                                                 const float* __restrict__ b3,
                                                 float* __restrict__ out) {
    __shared__ __align__(16) char smem[51200];
    float* PA   = (float*)smem;              // merge partials: 2 x [128][33] f32 (33792 B)
    bf16*  Wst  = (bf16*)smem;               // alias tail: [128][72] bf16 (18432 B)
    float* ost  = (float*)smem;              // alias out-stage: [32][132] f32 (16896 B)
    bf16*  Xsh  = (bf16*)(smem + 33792);     // [32][264] bf16 (16896 B)
    float* lbuf = (float*)(smem + 50688);    // [4][32] f32

    const int tid = threadIdx.x;
    const int kh = tid >> 6, lane = tid & 63;
    const int col = lane & 31, q = lane >> 5;
    const int b = blockIdx.x & 31, qt = blockIdx.x >> 5;
    const long qrow0 = (long)b * NN + qt * 32;
    const long kvrow = (long)b * NN;

    // Q B-fragments (cols = q-rows), same for all 4 waves
    bf16x8 Qb[8];
#pragma unroll
    for (int c = 0; c < 8; ++c)
        Qb[c] = *(const bf16x8*)&Pq[(qrow0 + col) * 128 + c * 16 + q * 8];

    f32x16 O[4];
#pragma unroll
    for (int mt = 0; mt < 4; ++mt)
#pragma unroll
        for (int r = 0; r < 16; ++r) O[mt][r] = 0.f;
    float lsum = 0.f;

    for (int kt = 0; kt < 8; ++kt) {
        int j0 = kh * 256 + kt * 32;
        // direct global fragment loads (16B/lane, L2-resident)
        bf16x8 kf[8];
#pragma unroll
        for (int c = 0; c < 8; ++c)
            kf[c] = *(const bf16x8*)&Xbf[(kvrow + j0 + col) * 128 + c * 16 + q * 8];
        bf16x8 vf[4][2];
#pragma unroll
        for (int mt = 0; mt < 4; ++mt)
#pragma unroll
            for (int kc = 0; kc < 2; ++kc)
                vf[mt][kc] = *(const bf16x8*)&Ptp[((long)b * DD + mt * 32 + col) * NN +
                                                  j0 + kc * 16 + q * 8];
        float tqs[16];
#pragma unroll
        for (int i = 0; i < 4; ++i) {
            float4 tv = *(const float4*)&t[kvrow + j0 + 8 * i + 4 * q];
            tqs[4 * i + 0] = tv.x; tqs[4 * i + 1] = tv.y;
            tqs[4 * i + 2] = tv.z; tqs[4 * i + 3] = tv.w;
        }
        f32x16 S;
#pragma unroll
        for (int r = 0; r < 16; ++r) S[r] = 0.f;
#pragma unroll
        for (int c = 0; c < 8; ++c) S = MFMA32(kf[c], Qb[c], S);

        float pv[16];
#pragma unroll
        for (int r = 0; r < 16; ++r) {
            float e = __expf(fminf(S[r] + tqs[r], 80.f));
            pv[r] = e;
            lsum += e;
        }
        bf16x4 Qd[4];
#pragma unroll
        for (int i = 0; i < 4; ++i)
#pragma unroll
            for (int e = 0; e < 4; ++e) Qd[i][e] = (bf16)pv[4 * i + e];
        bf16x4 sA = q ? Qd[0] : Qd[1];
        bf16x4 rA = swap32(sA);
        bf16x4 sB = q ? Qd[2] : Qd[3];
        bf16x4 rB = swap32(sB);
        bf16x4 lo0 = q ? rA : Qd[0], hi0 = q ? Qd[1] : rA;
        bf16x4 lo1 = q ? rB : Qd[2], hi1 = q ? Qd[3] : rB;
        bf16x8 f0, f1;
#pragma unroll
        for (int e = 0; e < 4; ++e) {
            f0[e] = lo0[e]; f0[4 + e] = hi0[e];
            f1[e] = lo1[e]; f1[4 + e] = hi1[e];
        }
#pragma unroll
        for (int mt = 0; mt < 4; ++mt) {
            O[mt] = MFMA32(vf[mt][0], f0, O[mt]);
            O[mt] = MFMA32(vf[mt][1], f1, O[mt]);
        }
    }

    // ---- two-stage fp32 merge of the 4 key-quarter partials ----
    float l2 = lsum + __shfl_xor(lsum, 32, 64);
    if (q == 0) lbuf[kh * 32 + col] = l2;
    if (kh & 1) {                       // waves 1,3 publish
        int slot = kh >> 1;
#pragma unroll
        for (int mt = 0; mt < 4; ++mt)
#pragma unroll
            for (int r = 0; r < 16; ++r) {
                int d = mt * 32 + (r & 3) + 8 * (r >> 2) + 4 * q;
                PA[slot * 4224 + d * 33 + col] = O[mt][r];
            }
    }
    __syncthreads();
    if (!(kh & 1)) {                    // waves 0,2 absorb
        int slot = kh >> 1;
#pragma unroll
        for (int mt = 0; mt < 4; ++mt)
#pragma unroll
            for (int r = 0; r < 16; ++r) {
                int d = mt * 32 + (r & 3) + 8 * (r >> 2) + 4 * q;
                O[mt][r] += PA[slot * 4224 + d * 33 + col];
            }
    }
    __syncthreads();
    if (kh == 2) {                      // wave 2 publishes its half-sum
#pragma unroll
        for (int mt = 0; mt < 4; ++mt)
#pragma unroll
            for (int r = 0; r < 16; ++r) {
                int d = mt * 32 + (r & 3) + 8 * (r >> 2) + 4 * q;
                PA[d * 33 + col] = O[mt][r];
            }
    } else if (kh & 1) {                // waves 1,3: stage P-half of X (coalesced)
        int t128 = (kh >> 1) * 64 + lane;
#pragma unroll
        for (int i = 0; i < 4; ++i) {
            int idx = t128 + i * 128;   // 0..511
            int row = idx >> 4, seg = idx & 15;
            *(bf16x8*)&Xsh[row * 264 + seg * 8] =
                *(const bf16x8*)&Xbf[(qrow0 + row) * 128 + seg * 8];
        }
    }
    __syncthreads();
    if (kh == 0) {                      // final sum + normalize + attn-half of X
        float ltot = lbuf[col] + lbuf[32 + col] + lbuf[64 + col] + lbuf[96 + col];
        float linv = 1.f / ltot;
#pragma unroll
        for (int mt = 0; mt < 4; ++mt)
#pragma unroll
            for (int r = 0; r < 16; ++r) {
                int d = mt * 32 + (r & 3) + 8 * (r >> 2) + 4 * q;
                float v = (O[mt][r] + PA[d * 33 + col]) * linv;
                Xsh[col * 264 + 128 + d] = (bf16)v;
            }
    }

    // ---- fused gated MLP on X=[P|attn]; W staged per (mat, 64-k phase) ----
    const int ln = lane & 15, q3 = lane >> 4;
    const int rh = kh & 1, ch = kh >> 1;  // wave: rows rh*16.., cols ch*64..
    f32x4 gz[4], gr[4];
    float rres[16];
#pragma unroll
    for (int mat = 0; mat < 3; ++mat) {
        f32x4 acc[4];
#pragma unroll
        for (int nt = 0; nt < 4; ++nt) acc[nt] = (f32x4){0.f, 0.f, 0.f, 0.f};
#pragma unroll
        for (int k2 = 0; k2 < 4; ++k2) {
            __syncthreads();            // first one also protects Xsh/PA reuse
#pragma unroll
            for (int i = 0; i < 4; ++i) {
                int idx = tid + i * 256;
                *(float4*)&Wst[(idx >> 3) * 72 + (idx & 7) * 8] =
                    *(const float4*)&WtG[(mat * 128 + (idx >> 3)) * 256 + k2 * 64 +
                                         (idx & 7) * 8];
            }
            __syncthreads();
#pragma unroll
            for (int kc2 = 0; kc2 < 2; ++kc2) {
                bf16x8 Af = *(const bf16x8*)&Xsh[(rh * 16 + ln) * 264 + k2 * 64 +
                                                 kc2 * 32 + q3 * 8];
#pragma unroll
                for (int nt = 0; nt < 4; ++nt) {
                    bf16x8 Bf = *(const bf16x8*)&Wst[(ch * 64 + nt * 16 + ln) * 72 +
                                                     kc2 * 32 + q3 * 8];
                    acc[nt] = MFMA16(Af, Bf, acc[nt]);
                }
            }
        }
        const float* bp = (mat == 0) ? b1 : ((mat == 1) ? b2 : b3);
#pragma unroll
        for (int nt = 0; nt < 4; ++nt) {
            int colc = ch * 64 + nt * 16 + ln;
            float bb = bp[colc];
#pragma unroll
            for (int r = 0; r < 4; ++r) {
                float y = acc[nt][r] + bb;
                if (mat == 0) gz[nt][r] = tanhf(y);
                else if (mat == 1) gr[nt][r] = 1.f / (1.f + __expf(-y));
                else {
                    float fg = 1.f / (1.f + __expf(-y));
                    int lrow = rh * 16 + q3 * 4 + r;
                    float p = (float)Xsh[lrow * 264 + colc];
                    rres[nt * 4 + r] = gr[nt][r] * p + fg * gz[nt][r];
                }
            }
        }
    }
    __syncthreads();                    // Wst dead -> out stage
#pragma unroll
    for (int nt = 0; nt < 4; ++nt)
#pragma unroll
        for (int r = 0; r < 4; ++r)
            ost[(rh * 16 + q3 * 4 + r) * 132 + ch * 64 + nt * 16 + ln] = rres[nt * 4 + r];
    __syncthreads();
#pragma unroll
    for (int i = 0; i < 4; ++i) {       // fully-coalesced float4 row stores
        int idx = tid + i * 256;        // 0..1023
        int row = idx >> 5, c4 = idx & 31;
        float4 v = *(const float4*)&ost[row * 132 + c4 * 4];
        *(float4*)&out[(qrow0 + row) * 128 + c4 * 4] = v;
    }
}

extern "C" void kernel_launch(void* const* d_in, const int* in_sizes, int n_in,
                              void* d_out, int out_size, void* d_ws, size_t ws_size,
                              hipStream_t stream) {
    const float* P     = (const float*)d_in[0];
    const float* w_itr = (const float*)d_in[1];
    const float* w1    = (const float*)d_in[2];
    const float* w2    = (const float*)d_in[3];
    const float* w3    = (const float*)d_in[4];
    const float* b1    = (const float*)d_in[5];
    const float* b2    = (const float*)d_in[6];
    const float* b3    = (const float*)d_in[7];
    float* out = (float*)d_out;

    char* wsb = (char*)d_ws;
    bf16* Xbf  = (bf16*)(wsb);                    //  8,388,608 B
    bf16* Pq   = (bf16*)(wsb + 8388608);          //  8,388,608 B
    bf16* Ptp  = (bf16*)(wsb + 16777216);         //  8,388,608 B
    float* tws = (float*)(wsb + 25165824);        //    131,072 B
    bf16* WtG  = (bf16*)(wsb + 25296896);         //    196,608 B

    k_prep<<<dim3(BB * 16), dim3(256), 0, stream>>>(P, w_itr, Xbf, Pq, Ptp, tws);
    k_prepw<<<dim3(96), dim3(256), 0, stream>>>(w1, w2, w3, WtG);
    k_attn<<<dim3(1024), dim3(256), 0, stream>>>(Xbf, Pq, Ptp, tws, WtG, b1, b2, b3, out);
}